// Round 6
// baseline (306.430 us; speedup 1.0000x reference)
//
#include <hip/hip_runtime.h>
#include <hip/hip_bf16.h>

// Problem: B=256, T=64, A=32, H=512, E=32
#define NB 256
#define NT 64
#define NA 32
#define NH 512
#define NE 32
#define MAXTILES 144   // max sum_e ceil(count_e/2) = 128 + 16

typedef short short8 __attribute__((ext_vector_type(8)));
typedef unsigned short ushort8v __attribute__((ext_vector_type(8)));
typedef float f32x4 __attribute__((ext_vector_type(4)));

__device__ __forceinline__ unsigned short f2bf(float f) {
  unsigned int u = __float_as_uint(f);
  u += 0x7FFFu + ((u >> 16) & 1u);   // round-to-nearest-even
  return (unsigned short)(u >> 16);
}
__device__ __forceinline__ float bf2f(unsigned short v) {
  return __uint_as_float(((unsigned int)v) << 16);
}

// async global->LDS, 16B per lane; lds dest = wave-uniform base + lane*16
__device__ __forceinline__ void gl2lds16(const void* g, void* l) {
  __builtin_amdgcn_global_load_lds(
      (const __attribute__((address_space(1))) unsigned int*)g,
      (__attribute__((address_space(3))) unsigned int*)l, 16, 0, 0);
}

// ---------------------------------------------------------------------------
// prep_all: blocks 0..4095 transpose W2; 4096..6143 W3; 6144..6399 W1;
// block 6400 does the expert grouping (tiles of 2 same-expert samples).
// W fp32 [e][K][512] -> Wt bf16 [e][512][K].
// ---------------------------------------------------------------------------
__global__ __launch_bounds__(256) void prep_all(
    const float* __restrict__ W1, const float* __restrict__ W2,
    const float* __restrict__ W3, unsigned short* __restrict__ Wt1,
    unsigned short* __restrict__ Wt2, unsigned short* __restrict__ Wt3,
    const int* __restrict__ cat, int* __restrict__ tiles,
    int* __restrict__ ntiles_out) {
  __shared__ __align__(16) unsigned char pmem[64 * 66 * 4];
  int bid = blockIdx.x;
  int tid = threadIdx.x;

  if (bid == 6400) {  // groupk
    int* cnt = (int*)pmem;            // [32]
    int* off = cnt + NE;              // [32]
    int* cur = off + NE;              // [32]
    int* order = cur + NE;            // [256]
    if (tid < NE) cnt[tid] = 0;
    __syncthreads();
    int e = cat[tid];
    atomicAdd(&cnt[e], 1);
    __syncthreads();
    if (tid == 0) {
      int s = 0;
      for (int i = 0; i < NE; i++) { off[i] = s; cur[i] = s; s += cnt[i]; }
    }
    __syncthreads();
    int p = atomicAdd(&cur[e], 1);
    order[p] = tid;
    __syncthreads();
    if (tid == 0) {
      int nt = 0;
      for (int i = 0; i < NE; i++) {
        for (int j = 0; j < cnt[i]; j += 2) {
          tiles[3 * nt + 0] = i;
          tiles[3 * nt + 1] = order[off[i] + j];
          tiles[3 * nt + 2] = (j + 1 < cnt[i]) ? order[off[i] + j + 1] : -1;
          nt++;
        }
      }
      *ntiles_out = nt;
    }
    return;
  }

  const float* W;
  unsigned short* Wt;
  int K, e, nt, kt;
  if (bid < 4096) {
    W = W2; Wt = Wt2; K = 1024;
    e = bid >> 7; kt = ((bid >> 3) & 15) * 64; nt = (bid & 7) * 64;
  } else if (bid < 6144) {
    int b = bid - 4096;
    W = W3; Wt = Wt3; K = 512;
    e = b >> 6; kt = ((b >> 3) & 7) * 64; nt = (b & 7) * 64;
  } else {
    int b = bid - 6144;
    W = W1; Wt = Wt1; K = 32;
    e = b >> 3; kt = 0; nt = (b & 7) * 64;
  }
  float* S = (float*)pmem;  // [64][66]
  int TK = (K - kt) < 64 ? (K - kt) : 64;  // 64 or 32 (W1)
  int units = TK * 32;                     // float2 units
  for (int u = tid; u < units; u += 256) {
    int k = u >> 5, c = u & 31;
    float2 v = *(const float2*)(W + ((size_t)e * K + kt + k) * NH + nt + 2 * c);
    *(float2*)(&S[k * 66 + 2 * c]) = v;
  }
  __syncthreads();
  int csh = (TK == 64) ? 3 : 2;  // chunks per row = TK/8
  int CHm = (1 << csh) - 1;
  int wunits = 64 << csh;
  for (int u = tid; u < wunits; u += 256) {
    int n = u >> csh, c = u & CHm;
    ushort8v pk;
#pragma unroll
    for (int j = 0; j < 8; j++) pk[j] = f2bf(S[(c * 8 + j) * 66 + n]);
    *(ushort8v*)(Wt + ((size_t)e * NH + nt + n) * K + kt + c * 8) = pk;
  }
}

// ---------------------------------------------------------------------------
// mid_kernel: blocks 0..511 = buildx (a_emb MFMA -> Xa);
// blocks 512..767 = taumv, SAMPLE-PARALLEL (one block per sample):
//   taubias[b][c] = tau_b . Wt2[e][c][512:] + b2[e][c]
// Per wave: 128 cols; per col the 64 lanes read the col's contiguous 1KB
// k-range as ONE coalesced b128, FMA vs register tau, 6-step shfl_xor
// butterfly. 128 independent iterations -> load ILP covers latency.
// ---------------------------------------------------------------------------
__global__ __launch_bounds__(256) void mid_kernel(
    const float* __restrict__ actions, const int* __restrict__ timesteps,
    const int* __restrict__ cat_ids, const unsigned short* __restrict__ Wt1,
    const float* __restrict__ b1, const unsigned short* __restrict__ Wt2,
    const float* __restrict__ b2, unsigned short* __restrict__ Xa,
    float* __restrict__ taubias) {
  // buildx LDS: phase1 Ws[256][32] (16384) + As[64][40] (5120);
  // phase2 Ts[64][264] (33792) aliases Ws (barrier separates phases).
  __shared__ __align__(16) unsigned char smem[33792 + 5120];
  int bid = blockIdx.x;
  int tid = threadIdx.x;
  const float kLog = 0.035977893400931146f;  // ln(10000)/256
  int wv = tid >> 6, l = tid & 63;

  if (bid >= 512) {
    // ---- taumv, one block per sample ----
    int b = bid - 512;
    int e = cat_ids[b];
    float tv = (float)timesteps[b];
    float tauv[8];
#pragma unroll
    for (int j = 0; j < 8; j++) {
      int k = l * 8 + j;  // 0..511
      float ang = tv * __expf(-(float)(k & 255) * kLog);
      tauv[j] = (k < 256) ? __sinf(ang) : __cosf(ang);
    }
    int c0 = wv * 128;
    const unsigned short* wp = Wt2 + ((size_t)(e * NH + c0)) * 1024 + 512 + l * 8;
    const float* b2p = b2 + (size_t)e * NH + c0;
    float* tb = taubias + (size_t)b * NH + c0;
#pragma unroll 4
    for (int ci = 0; ci < 128; ci++) {
      short8 w8 = *(const short8*)(wp + (size_t)ci * 1024);
      float sum = 0.f;
#pragma unroll
      for (int j = 0; j < 8; j++) sum += tauv[j] * bf2f((unsigned short)w8[j]);
#pragma unroll
      for (int d = 1; d < 64; d <<= 1) sum += __shfl_xor(sum, d, 64);
      if (l == 0) tb[ci] = sum + b2p[ci];
    }
    return;
  }

  // ---- buildx: a_emb = actions @ W1[e] + b1[e] -> Xa bf16 ----
  unsigned short* Ws = (unsigned short*)smem;                  // [256][32] swz
  unsigned short* As = (unsigned short*)(smem + 33792);        // [64][40]
  unsigned short* Ts = (unsigned short*)smem;                  // [64][264] alias
  int b = bid >> 1, h = bid & 1;
  int e = cat_ids[b];

  {  // async stage Wt1[e][h*256 .. +256][0..32] -> Ws (chunk swizzle)
    const unsigned short* wsrc = Wt1 + ((size_t)e * NH + h * 256) * NA;
#pragma unroll
    for (int j = 0; j < 4; j++) {
      int u = j * 256 + tid;
      int n = u >> 2, p = u & 3;
      int ch = p ^ ((n >> 1) & 3);
      gl2lds16(wsrc + (size_t)n * NA + ch * 8,
               Ws + (size_t)(j * 256 + (tid & 448)) * 8);
    }
  }
  {  // stage actions (64x32 f32 -> bf16), padded stride 40
    int row = tid >> 2, seg = tid & 3;
    const float* src = actions + (size_t)(b * NT + row) * NA + seg * 8;
    float4 v0 = *(const float4*)(src);
    float4 v1 = *(const float4*)(src + 4);
    ushort8v t;
    t[0] = f2bf(v0.x); t[1] = f2bf(v0.y); t[2] = f2bf(v0.z); t[3] = f2bf(v0.w);
    t[4] = f2bf(v1.x); t[5] = f2bf(v1.y); t[6] = f2bf(v1.z); t[7] = f2bf(v1.w);
    *(ushort8v*)(&As[row * 40 + seg * 8]) = t;
  }
  __syncthreads();

  int lrow = l & 15, kq = l >> 4;
  short8 af = *(short8*)(&As[(wv * 16 + lrow) * 40 + kq * 8]);
  f32x4 zero = {0.f, 0.f, 0.f, 0.f};
  f32x4 acc[16];
#pragma unroll
  for (int ni = 0; ni < 16; ni++) {
    int n = ni * 16 + lrow;
    int p = kq ^ ((n >> 1) & 3);
    short8 bfv = *(short8*)(&Ws[n * 32 + p * 8]);
    acc[ni] = __builtin_amdgcn_mfma_f32_16x16x32_bf16(af, bfv, zero, 0, 0, 0);
  }
  __syncthreads();  // Ws reads done; Ts aliases Ws
#pragma unroll
  for (int ni = 0; ni < 16; ni++) {
    int colL = ni * 16 + lrow;
    float bv = b1[(size_t)e * NH + h * 256 + colL];
#pragma unroll
    for (int r = 0; r < 4; r++) {
      int row = wv * 16 + kq * 4 + r;
      Ts[row * 264 + colL] = f2bf(acc[ni][r] + bv);
    }
  }
  __syncthreads();
#pragma unroll
  for (int i = 0; i < 8; i++) {  // coalesced rows
    int u = i * 256 + tid;
    int t2 = u >> 5, c4 = u & 31;
    uint4 v = *(uint4*)(&Ts[t2 * 264 + c4 * 8]);
    *(uint4*)(Xa + ((size_t)(b * NT + t2)) * NH + h * 256 + c4 * 8) = v;
  }
}

// ---------------------------------------------------------------------------
// Grouped GEMM v3: BM=128 (2 samples) x BN=128 x BK=64, K=512 fixed.
// 4 waves 2x2, each wave 64x64 out (4x4 MFMA tiles, 32 MFMA/iter).
// Staging: global_load_lds 16B only; XOR-swizzled LDS (<=2-way = free).
// Epilogue: LDS transpose -> coalesced uint4 (bf16: 2x64-col passes;
// fp32: 4x32-col passes).
// ---------------------------------------------------------------------------
template <int LDB, bool SWISH, bool OUT_BF16, bool TAUB>
__global__ __launch_bounds__(256) void gemm3_kernel(
    const unsigned short* __restrict__ X,   // (16384,512) bf16
    const unsigned short* __restrict__ Wt,  // (32,512,LDB) bf16
    const float* __restrict__ biasv,        // TAUB ? taubias(256,512) : b(32,512)
    void* __restrict__ Yv, const int* __restrict__ tiles,
    const int* __restrict__ pntiles) {
  __shared__ __align__(16) unsigned char smem[32768];
  unsigned short* As = (unsigned short*)smem;            // [128][64] swizzled
  unsigned short* Bs = (unsigned short*)(smem + 16384);  // [128][64] swizzled

  int bid = blockIdx.x;
  int ti = bid >> 2, q = bid & 3;
  if (ti >= *pntiles) return;
  int n0 = q * 128;
  int e = tiles[3 * ti], s0 = tiles[3 * ti + 1], s1 = tiles[3 * ti + 2];
  int s1v = (s1 < 0) ? s0 : s1;

  int tid = threadIdx.x;
  int wv = tid >> 6, l = tid & 63;
  int wr = wv >> 1, wc = wv & 1;
  int lr = l & 15, kq = l >> 4;

  f32x4 acc[4][4];
#pragma unroll
  for (int mi = 0; mi < 4; mi++)
#pragma unroll
    for (int ni = 0; ni < 4; ni++) acc[mi][ni] = (f32x4){0.f, 0.f, 0.f, 0.f};

  const unsigned short* wbase = Wt + ((size_t)e * NH + n0) * LDB;

  for (int it = 0; it < 8; it++) {
    int k0 = it * 64;
    __syncthreads();
    // A: 128 rows x 64 k = 16KB, 4 issues/thread
#pragma unroll
    for (int j = 0; j < 4; j++) {
      int u = j * 256 + tid;
      int row = u >> 3, p = u & 7;
      int ch = p ^ (row & 7);
      int s = (row < 64) ? s0 : s1v;
      gl2lds16(X + ((size_t)(s * NT + (row & 63))) * NH + k0 + ch * 8,
               As + (size_t)(j * 256 + (tid & 448)) * 8);
    }
    // B: 128 n x 64 k = 16KB, 4 issues/thread
#pragma unroll
    for (int j = 0; j < 4; j++) {
      int u = j * 256 + tid;
      int n = u >> 3, p = u & 7;
      int ch = p ^ (n & 7);
      gl2lds16(wbase + (size_t)n * LDB + k0 + ch * 8,
               Bs + (size_t)(j * 256 + (tid & 448)) * 8);
    }
    __syncthreads();

    short8 af[2][4], bf[2][4];
#pragma unroll
    for (int s2 = 0; s2 < 2; s2++) {
#pragma unroll
      for (int mi = 0; mi < 4; mi++) {
        int row = wr * 64 + mi * 16 + lr;
        int p = (s2 * 4 + kq) ^ (row & 7);
        af[s2][mi] = *(short8*)(&As[row * 64 + p * 8]);
      }
#pragma unroll
      for (int ni = 0; ni < 4; ni++) {
        int n = wc * 64 + ni * 16 + lr;
        int p = (s2 * 4 + kq) ^ (n & 7);
        bf[s2][ni] = *(short8*)(&Bs[n * 64 + p * 8]);
      }
    }
#pragma unroll
    for (int s2 = 0; s2 < 2; s2++)
#pragma unroll
      for (int mi = 0; mi < 4; mi++)
#pragma unroll
        for (int ni = 0; ni < 4; ni++)
          acc[mi][ni] = __builtin_amdgcn_mfma_f32_16x16x32_bf16(
              af[s2][mi], bf[s2][ni], acc[mi][ni], 0, 0, 0);
  }

  int sown = (wr == 0) ? s0 : s1;  // -1 => this wave's rows are duplicates

  if (OUT_BF16) {
    unsigned short* Ts = (unsigned short*)smem;  // [128][72]
    unsigned short* Y = (unsigned short*)Yv;
    for (int h = 0; h < 2; h++) {
      __syncthreads();
      if (wc == h && sown >= 0) {
#pragma unroll
        for (int ni = 0; ni < 4; ni++) {
          int colL = ni * 16 + lr;  // 0..63
          int col = n0 + h * 64 + colL;
          float bv = TAUB ? biasv[(size_t)sown * NH + col]
                          : biasv[(size_t)e * NH + col];
#pragma unroll
          for (int mi = 0; mi < 4; mi++)
#pragma unroll
            for (int r = 0; r < 4; r++) {
              int row = wr * 64 + mi * 16 + kq * 4 + r;
              float v = acc[mi][ni][r] + bv;
              if (SWISH) v = v / (1.f + __expf(-v));
              Ts[row * 72 + colL] = f2bf(v);
            }
        }
      }
      __syncthreads();
#pragma unroll
      for (int i = 0; i < 4; i++) {
        int u = i * 256 + tid;
        int row = u >> 3, c = u & 7;
        if (row >= 64 && s1 < 0) continue;
        int s = (row < 64) ? s0 : s1;
        uint4 v = *(uint4*)(&Ts[row * 72 + c * 8]);
        *(uint4*)(Y + ((size_t)(s * NT + (row & 63))) * NH + n0 + h * 64 +
                  c * 8) = v;
      }
    }
  } else {
    float* T32 = (float*)smem;  // [128][36]
    float* Y = (float*)Yv;
    for (int g = 0; g < 4; g++) {
      __syncthreads();
      if ((g >> 1) == wc && sown >= 0) {
#pragma unroll
        for (int nj = 0; nj < 2; nj++) {
          int ni = (g & 1) * 2 + nj;
          int colG = nj * 16 + lr;  // 0..31 within group
          int col = n0 + g * 32 + colG;
          float bv = TAUB ? biasv[(size_t)sown * NH + col]
                          : biasv[(size_t)e * NH + col];
#pragma unroll
          for (int mi = 0; mi < 4; mi++)
#pragma unroll
            for (int r = 0; r < 4; r++) {
              int row = wr * 64 + mi * 16 + kq * 4 + r;
              float v = acc[mi][ni][r] + bv;
              if (SWISH) v = v / (1.f + __expf(-v));
              T32[row * 36 + colG] = v;
            }
        }
      }
      __syncthreads();
#pragma unroll
      for (int i = 0; i < 4; i++) {
        int u = i * 256 + tid;
        int row = u >> 3, c = u & 7;  // 8 uint4 per row = 32 cols
        if (row >= 64 && s1 < 0) continue;
        int s = (row < 64) ? s0 : s1;
        uint4 v = *(uint4*)(&T32[row * 36 + c * 4]);
        *(uint4*)(Y + ((size_t)(s * NT + (row & 63))) * NH + n0 + g * 32 +
                  c * 4) = v;
      }
    }
  }
}

// ---------------------------------------------------------------------------
extern "C" void kernel_launch(void* const* d_in, const int* in_sizes, int n_in,
                              void* d_out, int out_size, void* d_ws, size_t ws_size,
                              hipStream_t stream) {
  const float* actions   = (const float*)d_in[0];
  const int*   timesteps = (const int*)d_in[1];
  const int*   cat_ids   = (const int*)d_in[2];
  const float* W1 = (const float*)d_in[3];
  const float* b1 = (const float*)d_in[4];
  const float* W2 = (const float*)d_in[5];
  const float* b2 = (const float*)d_in[6];
  const float* W3 = (const float*)d_in[7];
  const float* b3 = (const float*)d_in[8];

  // ws: Xa 16MB | Hb 16MB | Wt3 16MB | Wt1 1MB | taubias 512KB | tiles (~49.6MB)
  // Wt2 (32MB bf16, [e][n][1024]) lives in d_out (dead until gemmB writes it).
  unsigned short* Xa   = (unsigned short*)d_ws;
  unsigned short* Hb   = (unsigned short*)((char*)d_ws + (size_t)16777216);
  unsigned short* Wt3  = (unsigned short*)((char*)d_ws + (size_t)33554432);
  unsigned short* Wt1  = (unsigned short*)((char*)d_ws + (size_t)50331648);
  float*          taub = (float*)((char*)d_ws + (size_t)51380224);
  int* tiles  = (int*)((char*)d_ws + (size_t)51904512);
  int* ntiles = tiles + 3 * MAXTILES;
  unsigned short* Wt2 = (unsigned short*)d_out;  // exact 32MB fit

  prep_all<<<6401, 256, 0, stream>>>(W1, W2, W3, Wt1, Wt2, Wt3,
                                     cat_ids, tiles, ntiles);
  mid_kernel<<<768, 256, 0, stream>>>(actions, timesteps, cat_ids, Wt1, b1,
                                      Wt2, b2, Xa, taub);
  gemm3_kernel<1024, true, true, true><<<MAXTILES * 4, 256, 0, stream>>>(
      Xa, Wt2, taub, (void*)Hb, tiles, ntiles);
  gemm3_kernel<512, false, false, false><<<MAXTILES * 4, 256, 0, stream>>>(
      Hb, Wt3, b3, d_out, tiles, ntiles);
}

// Round 7
// 263.758 us; speedup vs baseline: 1.1618x; 1.1618x over previous
//
#include <hip/hip_runtime.h>
#include <hip/hip_bf16.h>

// Problem: B=256, T=64, A=32, H=512, E=32
#define NB 256
#define NT 64
#define NA 32
#define NH 512
#define NE 32
#define MAXTILES 144   // pair-tiles: max sum_e ceil(count_e/2)
#define MAXT16 48      // 16-sample tiles: max sum_e ceil(count_e/16)

typedef short short8 __attribute__((ext_vector_type(8)));
typedef unsigned short ushort8v __attribute__((ext_vector_type(8)));
typedef float f32x4 __attribute__((ext_vector_type(4)));

__device__ __forceinline__ unsigned short f2bf(float f) {
  unsigned int u = __float_as_uint(f);
  u += 0x7FFFu + ((u >> 16) & 1u);   // round-to-nearest-even
  return (unsigned short)(u >> 16);
}
__device__ __forceinline__ float bf2f(unsigned short v) {
  return __uint_as_float(((unsigned int)v) << 16);
}

// async global->LDS, 16B per lane; lds dest = wave-uniform base + lane*16
__device__ __forceinline__ void gl2lds16(const void* g, void* l) {
  __builtin_amdgcn_global_load_lds(
      (const __attribute__((address_space(1))) unsigned int*)g,
      (__attribute__((address_space(3))) unsigned int*)l, 16, 0, 0);
}

// ---------------------------------------------------------------------------
// prep_all: blocks 0..4095 transpose W2; 4096..6143 W3; 6144..6399 W1;
// block 6400: expert grouping -> pair-tiles (gemm3), 16-sample tiles (taumv),
// and the grouped sample order.
// ---------------------------------------------------------------------------
__global__ __launch_bounds__(256) void prep_all(
    const float* __restrict__ W1, const float* __restrict__ W2,
    const float* __restrict__ W3, unsigned short* __restrict__ Wt1,
    unsigned short* __restrict__ Wt2, unsigned short* __restrict__ Wt3,
    const int* __restrict__ cat, int* __restrict__ tiles,
    int* __restrict__ ntiles_out, int* __restrict__ order_g,
    int* __restrict__ t16, int* __restrict__ nt16_out) {
  __shared__ __align__(16) unsigned char pmem[64 * 66 * 4];
  int bid = blockIdx.x;
  int tid = threadIdx.x;

  if (bid == 6400) {  // grouping
    int* cnt = (int*)pmem;            // [32]
    int* off = cnt + NE;              // [32]
    int* cur = off + NE;              // [32]
    int* order = cur + NE;            // [256]
    if (tid < NE) cnt[tid] = 0;
    __syncthreads();
    int e = cat[tid];
    atomicAdd(&cnt[e], 1);
    __syncthreads();
    if (tid == 0) {
      int s = 0;
      for (int i = 0; i < NE; i++) { off[i] = s; cur[i] = s; s += cnt[i]; }
    }
    __syncthreads();
    int p = atomicAdd(&cur[e], 1);
    order[p] = tid;
    __syncthreads();
    order_g[tid] = order[tid];
    if (tid == 0) {
      int nt = 0;
      for (int i = 0; i < NE; i++)
        for (int j = 0; j < cnt[i]; j += 2) {
          tiles[3 * nt + 0] = i;
          tiles[3 * nt + 1] = order[off[i] + j];
          tiles[3 * nt + 2] = (j + 1 < cnt[i]) ? order[off[i] + j + 1] : -1;
          nt++;
        }
      *ntiles_out = nt;
      int n2 = 0;
      for (int i = 0; i < NE; i++)
        for (int j = 0; j < cnt[i]; j += 16) {
          t16[3 * n2 + 0] = i;
          t16[3 * n2 + 1] = off[i] + j;
          t16[3 * n2 + 2] = (cnt[i] - j < 16) ? (cnt[i] - j) : 16;
          n2++;
        }
      *nt16_out = n2;
    }
    return;
  }

  const float* W;
  unsigned short* Wt;
  int K, e, nt, kt;
  if (bid < 4096) {
    W = W2; Wt = Wt2; K = 1024;
    e = bid >> 7; kt = ((bid >> 3) & 15) * 64; nt = (bid & 7) * 64;
  } else if (bid < 6144) {
    int b = bid - 4096;
    W = W3; Wt = Wt3; K = 512;
    e = b >> 6; kt = ((b >> 3) & 7) * 64; nt = (b & 7) * 64;
  } else {
    int b = bid - 6144;
    W = W1; Wt = Wt1; K = 32;
    e = b >> 3; kt = 0; nt = (b & 7) * 64;
  }
  float* S = (float*)pmem;  // [64][66]
  int TK = (K - kt) < 64 ? (K - kt) : 64;  // 64 or 32 (W1)
  int units = TK * 32;                     // float2 units
  for (int u = tid; u < units; u += 256) {
    int k = u >> 5, c = u & 31;
    float2 v = *(const float2*)(W + ((size_t)e * K + kt + k) * NH + nt + 2 * c);
    *(float2*)(&S[k * 66 + 2 * c]) = v;
  }
  __syncthreads();
  int csh = (TK == 64) ? 3 : 2;  // chunks per row = TK/8
  int CHm = (1 << csh) - 1;
  int wunits = 64 << csh;
  for (int u = tid; u < wunits; u += 256) {
    int n = u >> csh, c = u & CHm;
    ushort8v pk;
#pragma unroll
    for (int j = 0; j < 8; j++) pk[j] = f2bf(S[(c * 8 + j) * 66 + n]);
    *(ushort8v*)(Wt + ((size_t)e * NH + nt + n) * K + kt + c * 8) = pk;
  }
}

// ---------------------------------------------------------------------------
// mid_kernel: blocks 0..511 = buildx (a_emb MFMA -> Xa);
// blocks 512..559 = taumv via MFMA (grouped 16-sample tiles):
//   taubias[s][c] = tau_s . Wt2[e][c][512:] + b2[e][c]
// MFMA does the K-reduction in hardware (replaces the serial shfl butterfly
// that was 81us). Per tile: Tau(16x512, LDS) x Wt2-cols; per wave 128 cols =
// 8 chunks x 16 k-steps of 16x16x32, B-frags straight from global
// (lane-contiguous 16B). ~400 MFLOP total.
// ---------------------------------------------------------------------------
__global__ __launch_bounds__(256) void mid_kernel(
    const float* __restrict__ actions, const int* __restrict__ timesteps,
    const int* __restrict__ cat_ids, const unsigned short* __restrict__ Wt1,
    const float* __restrict__ b1, const unsigned short* __restrict__ Wt2,
    const float* __restrict__ b2, unsigned short* __restrict__ Xa,
    float* __restrict__ taubias, const int* __restrict__ order_g,
    const int* __restrict__ t16, const int* __restrict__ pnt16) {
  // buildx: phase1 Ws[256][32] (16384) + As[64][40] (5120);
  //         phase2 Ts[64][264] (33792) aliases Ws.
  // taumv:  tauS[16][520] bf16 (16640) + sids[16] + tvs[16].
  __shared__ __align__(16) unsigned char smem[33792 + 5120];
  int bid = blockIdx.x;
  int tid = threadIdx.x;
  const float kLog = 0.035977893400931146f;  // ln(10000)/256
  int wv = tid >> 6, l = tid & 63;
  int lr = l & 15, kq = l >> 4;

  if (bid >= 512) {
    int t = bid - 512;
    if (t >= *pnt16) return;
    int e = t16[3 * t], start = t16[3 * t + 1], m = t16[3 * t + 2];
    unsigned short* tauS = (unsigned short*)smem;       // [16][520]
    int* sids = (int*)(smem + 16640);                   // [16]
    float* tvs = (float*)(smem + 16640 + 64);           // [16]
    if (tid < 16) {
      int sid = (tid < m) ? order_g[start + tid] : -1;
      sids[tid] = sid;
      tvs[tid] = (sid >= 0) ? (float)timesteps[sid] : 0.f;
    }
    __syncthreads();
    {  // stage tau bf16: slot = tid>>4 owns k-range [ (tid&15)*32, +32 )
      int slot = tid >> 4, kp = (tid & 15) * 32;
      float tv = tvs[slot];
#pragma unroll
      for (int j = 0; j < 32; j++) {
        int k = kp + j;
        float ang = tv * __expf(-(float)(k & 255) * kLog);
        float v = (k < 256) ? __sinf(ang) : __cosf(ang);
        tauS[slot * 520 + k] = f2bf(v);
      }
    }
    __syncthreads();

    int c0 = wv * 128;
    f32x4 acc[8];
#pragma unroll
    for (int ch = 0; ch < 8; ch++) acc[ch] = (f32x4){0.f, 0.f, 0.f, 0.f};
    // B-frag: lane reads Wt2[e][c0+ch*16+lr][512 + ks*32 + kq*8 .. +8]
    const unsigned short* wbase =
        Wt2 + ((size_t)(e * NH + c0)) * 1024 + 512 + kq * 8;
#pragma unroll
    for (int ks = 0; ks < 16; ks++) {
      short8 a = *(short8*)(&tauS[lr * 520 + ks * 32 + kq * 8]);
#pragma unroll
      for (int ch = 0; ch < 8; ch++) {
        short8 b = *(const short8*)(wbase + (size_t)(ch * 16 + lr) * 1024 +
                                    ks * 32);
        acc[ch] = __builtin_amdgcn_mfma_f32_16x16x32_bf16(a, b, acc[ch], 0, 0, 0);
      }
    }
#pragma unroll
    for (int ch = 0; ch < 8; ch++) {
      int col = c0 + ch * 16 + lr;
      float bv = b2[(size_t)e * NH + col];
#pragma unroll
      for (int r = 0; r < 4; r++) {
        int slot = kq * 4 + r;
        int sid = sids[slot];
        if (sid >= 0) taubias[(size_t)sid * NH + col] = acc[ch][r] + bv;
      }
    }
    return;
  }

  // ---- buildx: a_emb = actions @ W1[e] + b1[e] -> Xa bf16 ----
  unsigned short* Ws = (unsigned short*)smem;                  // [256][32] swz
  unsigned short* As = (unsigned short*)(smem + 33792);        // [64][40]
  unsigned short* Ts = (unsigned short*)smem;                  // [64][264] alias
  int b = bid >> 1, h = bid & 1;
  int e = cat_ids[b];

  {  // async stage Wt1[e][h*256 .. +256][0..32] -> Ws (chunk swizzle)
    const unsigned short* wsrc = Wt1 + ((size_t)e * NH + h * 256) * NA;
#pragma unroll
    for (int j = 0; j < 4; j++) {
      int u = j * 256 + tid;
      int n = u >> 2, p = u & 3;
      int ch = p ^ ((n >> 1) & 3);
      gl2lds16(wsrc + (size_t)n * NA + ch * 8,
               Ws + (size_t)(j * 256 + (tid & 448)) * 8);
    }
  }
  {  // stage actions (64x32 f32 -> bf16), padded stride 40
    int row = tid >> 2, seg = tid & 3;
    const float* src = actions + (size_t)(b * NT + row) * NA + seg * 8;
    float4 v0 = *(const float4*)(src);
    float4 v1 = *(const float4*)(src + 4);
    ushort8v t;
    t[0] = f2bf(v0.x); t[1] = f2bf(v0.y); t[2] = f2bf(v0.z); t[3] = f2bf(v0.w);
    t[4] = f2bf(v1.x); t[5] = f2bf(v1.y); t[6] = f2bf(v1.z); t[7] = f2bf(v1.w);
    *(ushort8v*)(&As[row * 40 + seg * 8]) = t;
  }
  __syncthreads();

  short8 af = *(short8*)(&As[(wv * 16 + lr) * 40 + kq * 8]);
  f32x4 zero = {0.f, 0.f, 0.f, 0.f};
  f32x4 acc[16];
#pragma unroll
  for (int ni = 0; ni < 16; ni++) {
    int n = ni * 16 + lr;
    int p = kq ^ ((n >> 1) & 3);
    short8 bfv = *(short8*)(&Ws[n * 32 + p * 8]);
    acc[ni] = __builtin_amdgcn_mfma_f32_16x16x32_bf16(af, bfv, zero, 0, 0, 0);
  }
  __syncthreads();  // Ws reads done; Ts aliases Ws
#pragma unroll
  for (int ni = 0; ni < 16; ni++) {
    int colL = ni * 16 + lr;
    float bv = b1[(size_t)e * NH + h * 256 + colL];
#pragma unroll
    for (int r = 0; r < 4; r++) {
      int row = wv * 16 + kq * 4 + r;
      Ts[row * 264 + colL] = f2bf(acc[ni][r] + bv);
    }
  }
  __syncthreads();
#pragma unroll
  for (int i = 0; i < 8; i++) {  // coalesced rows
    int u = i * 256 + tid;
    int t2 = u >> 5, c4 = u & 31;
    uint4 v = *(uint4*)(&Ts[t2 * 264 + c4 * 8]);
    *(uint4*)(Xa + ((size_t)(b * NT + t2)) * NH + h * 256 + c4 * 8) = v;
  }
}

// ---------------------------------------------------------------------------
// Grouped GEMM v3: BM=128 (2 samples) x BN=128 x BK=64, K=512 fixed.
// 4 waves 2x2, each wave 64x64 out (4x4 MFMA tiles, 32 MFMA/iter).
// Staging: global_load_lds 16B only; XOR-swizzled LDS (<=2-way = free).
// Epilogue: LDS transpose -> coalesced uint4.
// ---------------------------------------------------------------------------
template <int LDB, bool SWISH, bool OUT_BF16, bool TAUB>
__global__ __launch_bounds__(256) void gemm3_kernel(
    const unsigned short* __restrict__ X,   // (16384,512) bf16
    const unsigned short* __restrict__ Wt,  // (32,512,LDB) bf16
    const float* __restrict__ biasv,        // TAUB ? taubias(256,512) : b(32,512)
    void* __restrict__ Yv, const int* __restrict__ tiles,
    const int* __restrict__ pntiles) {
  __shared__ __align__(16) unsigned char smem[32768];
  unsigned short* As = (unsigned short*)smem;            // [128][64] swizzled
  unsigned short* Bs = (unsigned short*)(smem + 16384);  // [128][64] swizzled

  int bid = blockIdx.x;
  int ti = bid >> 2, q = bid & 3;
  if (ti >= *pntiles) return;
  int n0 = q * 128;
  int e = tiles[3 * ti], s0 = tiles[3 * ti + 1], s1 = tiles[3 * ti + 2];
  int s1v = (s1 < 0) ? s0 : s1;

  int tid = threadIdx.x;
  int wv = tid >> 6, l = tid & 63;
  int wr = wv >> 1, wc = wv & 1;
  int lr = l & 15, kq = l >> 4;

  f32x4 acc[4][4];
#pragma unroll
  for (int mi = 0; mi < 4; mi++)
#pragma unroll
    for (int ni = 0; ni < 4; ni++) acc[mi][ni] = (f32x4){0.f, 0.f, 0.f, 0.f};

  const unsigned short* wbase = Wt + ((size_t)e * NH + n0) * LDB;

  for (int it = 0; it < 8; it++) {
    int k0 = it * 64;
    __syncthreads();
    // A: 128 rows x 64 k = 16KB, 4 issues/thread
#pragma unroll
    for (int j = 0; j < 4; j++) {
      int u = j * 256 + tid;
      int row = u >> 3, p = u & 7;
      int ch = p ^ (row & 7);
      int s = (row < 64) ? s0 : s1v;
      gl2lds16(X + ((size_t)(s * NT + (row & 63))) * NH + k0 + ch * 8,
               As + (size_t)(j * 256 + (tid & 448)) * 8);
    }
    // B: 128 n x 64 k = 16KB, 4 issues/thread
#pragma unroll
    for (int j = 0; j < 4; j++) {
      int u = j * 256 + tid;
      int n = u >> 3, p = u & 7;
      int ch = p ^ (n & 7);
      gl2lds16(wbase + (size_t)n * LDB + k0 + ch * 8,
               Bs + (size_t)(j * 256 + (tid & 448)) * 8);
    }
    __syncthreads();

    short8 af[2][4], bf[2][4];
#pragma unroll
    for (int s2 = 0; s2 < 2; s2++) {
#pragma unroll
      for (int mi = 0; mi < 4; mi++) {
        int row = wr * 64 + mi * 16 + lr;
        int p = (s2 * 4 + kq) ^ (row & 7);
        af[s2][mi] = *(short8*)(&As[row * 64 + p * 8]);
      }
#pragma unroll
      for (int ni = 0; ni < 4; ni++) {
        int n = wc * 64 + ni * 16 + lr;
        int p = (s2 * 4 + kq) ^ (n & 7);
        bf[s2][ni] = *(short8*)(&Bs[n * 64 + p * 8]);
      }
    }
#pragma unroll
    for (int s2 = 0; s2 < 2; s2++)
#pragma unroll
      for (int mi = 0; mi < 4; mi++)
#pragma unroll
        for (int ni = 0; ni < 4; ni++)
          acc[mi][ni] = __builtin_amdgcn_mfma_f32_16x16x32_bf16(
              af[s2][mi], bf[s2][ni], acc[mi][ni], 0, 0, 0);
  }

  int sown = (wr == 0) ? s0 : s1;  // -1 => this wave's rows are duplicates

  if (OUT_BF16) {
    unsigned short* Ts = (unsigned short*)smem;  // [128][72]
    unsigned short* Y = (unsigned short*)Yv;
    for (int h = 0; h < 2; h++) {
      __syncthreads();
      if (wc == h && sown >= 0) {
#pragma unroll
        for (int ni = 0; ni < 4; ni++) {
          int colL = ni * 16 + lr;  // 0..63
          int col = n0 + h * 64 + colL;
          float bv = TAUB ? biasv[(size_t)sown * NH + col]
                          : biasv[(size_t)e * NH + col];
#pragma unroll
          for (int mi = 0; mi < 4; mi++)
#pragma unroll
            for (int r = 0; r < 4; r++) {
              int row = wr * 64 + mi * 16 + kq * 4 + r;
              float v = acc[mi][ni][r] + bv;
              if (SWISH) v = v / (1.f + __expf(-v));
              Ts[row * 72 + colL] = f2bf(v);
            }
        }
      }
      __syncthreads();
#pragma unroll
      for (int i = 0; i < 4; i++) {
        int u = i * 256 + tid;
        int row = u >> 3, c = u & 7;
        if (row >= 64 && s1 < 0) continue;
        int s = (row < 64) ? s0 : s1;
        uint4 v = *(uint4*)(&Ts[row * 72 + c * 8]);
        *(uint4*)(Y + ((size_t)(s * NT + (row & 63))) * NH + n0 + h * 64 +
                  c * 8) = v;
      }
    }
  } else {
    float* T32 = (float*)smem;  // [128][36]
    float* Y = (float*)Yv;
    for (int g = 0; g < 4; g++) {
      __syncthreads();
      if ((g >> 1) == wc && sown >= 0) {
#pragma unroll
        for (int nj = 0; nj < 2; nj++) {
          int ni = (g & 1) * 2 + nj;
          int colG = nj * 16 + lr;  // 0..31 within group
          int col = n0 + g * 32 + colG;
          float bv = TAUB ? biasv[(size_t)sown * NH + col]
                          : biasv[(size_t)e * NH + col];
#pragma unroll
          for (int mi = 0; mi < 4; mi++)
#pragma unroll
            for (int r = 0; r < 4; r++) {
              int row = wr * 64 + mi * 16 + kq * 4 + r;
              float v = acc[mi][ni][r] + bv;
              if (SWISH) v = v / (1.f + __expf(-v));
              T32[row * 36 + colG] = v;
            }
        }
      }
      __syncthreads();
#pragma unroll
      for (int i = 0; i < 4; i++) {
        int u = i * 256 + tid;
        int row = u >> 3, c = u & 7;  // 8 uint4 per row = 32 cols
        if (row >= 64 && s1 < 0) continue;
        int s = (row < 64) ? s0 : s1;
        uint4 v = *(uint4*)(&T32[row * 36 + c * 4]);
        *(uint4*)(Y + ((size_t)(s * NT + (row & 63))) * NH + n0 + g * 32 +
                  c * 4) = v;
      }
    }
  }
}

// ---------------------------------------------------------------------------
extern "C" void kernel_launch(void* const* d_in, const int* in_sizes, int n_in,
                              void* d_out, int out_size, void* d_ws, size_t ws_size,
                              hipStream_t stream) {
  const float* actions   = (const float*)d_in[0];
  const int*   timesteps = (const int*)d_in[1];
  const int*   cat_ids   = (const int*)d_in[2];
  const float* W1 = (const float*)d_in[3];
  const float* b1 = (const float*)d_in[4];
  const float* W2 = (const float*)d_in[5];
  const float* b2 = (const float*)d_in[6];
  const float* W3 = (const float*)d_in[7];
  const float* b3 = (const float*)d_in[8];

  // ws: Xa 16MB | Hb 16MB | Wt3 16MB | Wt1 1MB | taubias 512KB | meta (~52MB)
  // Wt2 (32MB bf16, [e][n][1024]) lives in d_out (dead until gemmB writes it).
  unsigned short* Xa   = (unsigned short*)d_ws;
  unsigned short* Hb   = (unsigned short*)((char*)d_ws + (size_t)16777216);
  unsigned short* Wt3  = (unsigned short*)((char*)d_ws + (size_t)33554432);
  unsigned short* Wt1  = (unsigned short*)((char*)d_ws + (size_t)50331648);
  float*          taub = (float*)((char*)d_ws + (size_t)51380224);
  int* tiles   = (int*)((char*)d_ws + (size_t)51904512);   // 3*144 ints
  int* ntiles  = tiles + 3 * MAXTILES;
  int* order_g = ntiles + 1;                                // 256 ints
  int* t16     = order_g + NB;                              // 3*48 ints
  int* nt16    = t16 + 3 * MAXT16;
  unsigned short* Wt2 = (unsigned short*)d_out;  // exact 32MB fit

  prep_all<<<6401, 256, 0, stream>>>(W1, W2, W3, Wt1, Wt2, Wt3, cat_ids,
                                     tiles, ntiles, order_g, t16, nt16);
  mid_kernel<<<512 + MAXT16, 256, 0, stream>>>(
      actions, timesteps, cat_ids, Wt1, b1, Wt2, b2, Xa, taub, order_g, t16,
      nt16);
  gemm3_kernel<1024, true, true, true><<<MAXTILES * 4, 256, 0, stream>>>(
      Xa, Wt2, taub, (void*)Hb, tiles, ntiles);
  gemm3_kernel<512, false, false, false><<<MAXTILES * 4, 256, 0, stream>>>(
      Hb, Wt3, b3, d_out, tiles, ntiles);
}